// Round 8
// baseline (571.945 us; speedup 1.0000x reference)
//
#include <hip/hip_runtime.h>
#include <hip/hip_fp16.h>

#ifndef __has_builtin
#define __has_builtin(x) 0
#endif

#if __has_builtin(__builtin_amdgcn_exp2f)
#define EXP2F(x) __builtin_amdgcn_exp2f(x)
#else
#define EXP2F(x) exp2f(x)
#endif

#if __has_builtin(__builtin_amdgcn_rcpf)
#define RCPF(x) __builtin_amdgcn_rcpf(x)
#else
#define RCPF(x) (1.0f / (x))
#endif

namespace {

constexpr int kB = 65536;
constexpr int kT = 50;
constexpr int kI = 2;
constexpr int kH = 20;
constexpr int kO = 2;
constexpr int kGB = 64;    // batch elements per block

__device__ __forceinline__ float fast_tanh(float v) {
    // tanh(v) = 1 - 2/(exp(2v)+1); v_exp_f32 saturates so no clamp needed
    const float p = EXP2F(v * 2.8853900817779268f);
    return fmaf(-2.0f, RCPF(p + 1.0f), 1.0f);
}

// Intra-quad lane exchange via DPP quad_perm (pure VALU, no DS latency).
// xor1: [1,0,3,2]=0xB1  xor2: [2,3,0,1]=0x4E  xor3: [3,2,1,0]=0x1B
#if __has_builtin(__builtin_amdgcn_mov_dpp)
template <int CTRL>
__device__ __forceinline__ float fqp(float v) {
    return __int_as_float(
        __builtin_amdgcn_mov_dpp(__float_as_int(v), CTRL, 0xF, 0xF, true));
}
#else
template <int CTRL>
__device__ __forceinline__ float fqp(float v) {
    constexpr int d = (CTRL == 0xB1) ? 1 : (CTRL == 0x4E) ? 2 : 3;
    return __shfl_xor(v, d);
}
#endif

// 4 threads (one quad) per batch element; thread sub owns hidden rows
// 4*i+sub. W_hh held as f16 PAIRS (50 VGPRs instead of 100) and consumed
// via fmaf(__low2float(...)) -> v_fma_mix_f32 (same instr count, half the
// registers => 4 waves/SIMD instead of 3). Columns permuted for DPP gather:
//   wh[i][r][p] = {W_hh[(4i+sub)*20 + 4r + (sub^2p)], ... (sub^(2p+1))}
//   v_d         = quad_perm-xor(h_own[r], d) == h_{4r + (sub^d)}
__global__ __launch_bounds__(256)
__attribute__((amdgpu_waves_per_eu(4)))
void dprnn_kernel(
    const float* __restrict__ x, const float* __restrict__ W_ih,
    const float* __restrict__ W_hh, const float* __restrict__ b_ih,
    const float* __restrict__ b_hh, const float* __restrict__ W_out,
    const float* __restrict__ b_out, const float* __restrict__ mask,
    float* __restrict__ out)
{
    __shared__ __align__(16) float lds_o[kGB * kT * kO];  // 25600 B

    const int tidx = threadIdx.x;
    const int gl   = tidx >> 2;          // quad index 0..63
    const int sub  = tidx & 3;           // quarter of H owned
    const size_t g = (size_t)blockIdx.x * kGB + gl;

    // ---- weights into registers (f16 pairs, column-permuted) ----
    __half2 wh[5][5][2];
    __half2 wi2[5], wo2[5];
    float bia[5];
#pragma unroll
    for (int i = 0; i < 5; ++i) {
        const int row = 4 * i + sub;
#pragma unroll
        for (int r = 0; r < 5; ++r) {
            wh[i][r][0] = __floats2half2_rn(W_hh[row * kH + 4 * r + (sub ^ 0)],
                                            W_hh[row * kH + 4 * r + (sub ^ 1)]);
            wh[i][r][1] = __floats2half2_rn(W_hh[row * kH + 4 * r + (sub ^ 2)],
                                            W_hh[row * kH + 4 * r + (sub ^ 3)]);
        }
        wi2[i] = __floats2half2_rn(W_ih[row * kI + 0], W_ih[row * kI + 1]);
        wo2[i] = __floats2half2_rn(W_out[row], W_out[kH + row]);
        bia[i] = b_ih[row] + b_hh[row];
    }
    const float bo0 = b_out[0];
    const float bo1 = b_out[1];

    float h[5] = {0.f, 0.f, 0.f, 0.f, 0.f};

    const float* mp = mask + g * (kT * kH) + sub;
    const float* xp = x + g * (kT * kI);

    // one RNN step; m = this step's dropout mask (rows 4r+sub), x0/x1 = x_t
    auto step = [&](const float m[5], float x0, float x1, int t) {
        float acc[5];
#pragma unroll
        for (int i = 0; i < 5; ++i)
            acc[i] = fmaf(__low2float(wi2[i]), x0,
                          fmaf(__high2float(wi2[i]), x1, bia[i]));
#pragma unroll
        for (int r = 0; r < 5; ++r) {
            const float v0 = h[r];
            const float v1 = fqp<0xB1>(h[r]);
            const float v2 = fqp<0x4E>(h[r]);
            const float v3 = fqp<0x1B>(h[r]);
#pragma unroll
            for (int i = 0; i < 5; ++i) {
                acc[i] = fmaf(__low2float(wh[i][r][0]), v0, acc[i]);
                acc[i] = fmaf(__high2float(wh[i][r][0]), v1, acc[i]);
                acc[i] = fmaf(__low2float(wh[i][r][1]), v2, acc[i]);
                acc[i] = fmaf(__high2float(wh[i][r][1]), v3, acc[i]);
            }
        }
        float p0 = 0.f, p1 = 0.f;
#pragma unroll
        for (int i = 0; i < 5; ++i) {
            const float hn = fast_tanh(acc[i]);
            h[i] = hn;
            const float dm = hn * m[i];
            p0 = fmaf(dm, __low2float(wo2[i]), p0);
            p1 = fmaf(dm, __high2float(wo2[i]), p1);
        }
        p0 += fqp<0xB1>(p0);
        p0 += fqp<0x4E>(p0);
        p1 += fqp<0xB1>(p1);
        p1 += fqp<0x4E>(p1);
        if (sub == 0)
            *(float2*)&lds_o[gl * (kT * kO) + t * kO] =
                make_float2(p0 + bo0, p1 + bo1);
    };

    // ---- prologue: masks for t=0,1 and x for t=0,1 ----
    float m0[5], m1[5];
#pragma unroll
    for (int r = 0; r < 5; ++r) m0[r] = mp[0 * kH + 4 * r];
#pragma unroll
    for (int r = 0; r < 5; ++r) m1[r] = mp[1 * kH + 4 * r];
    float4 xq = *(const float4*)xp;

    // ---- main: 24 blocks of 2 steps with distance-2 prefetch ----
    for (int tb = 0; tb < kT - 2; tb += 2) {
        float n0[5], n1[5];
        const float* mq = mp + (tb + 2) * kH;
#pragma unroll
        for (int r = 0; r < 5; ++r) n0[r] = mq[4 * r];
#pragma unroll
        for (int r = 0; r < 5; ++r) n1[r] = mq[kH + 4 * r];
        const float4 xn = *(const float4*)(xp + (tb + 2) * kI);

        step(m0, xq.x, xq.y, tb);
        step(m1, xq.z, xq.w, tb + 1);

#pragma unroll
        for (int r = 0; r < 5; ++r) { m0[r] = n0[r]; m1[r] = n1[r]; }
        xq = xn;
    }
    // tail: t = 48, 49
    step(m0, xq.x, xq.y, kT - 2);
    step(m1, xq.z, xq.w, kT - 1);

    // ---- coalesced writeback of this block's 64*100 floats ----
    __syncthreads();
    float* ob = out + (size_t)blockIdx.x * (kGB * kT * kO);
#pragma unroll
    for (int it = 0; it < 6; ++it) {
        const int idx = it * 1024 + tidx * 4;
        const float4 v = *(const float4*)&lds_o[idx];
        *(float4*)(ob + idx) = v;
    }
    {
        const int idx = 6144 + tidx;
        ob[idx] = lds_o[idx];
    }
}

}  // namespace

extern "C" void kernel_launch(void* const* d_in, const int* in_sizes, int n_in,
                              void* d_out, int out_size, void* d_ws, size_t ws_size,
                              hipStream_t stream) {
    const float* x     = (const float*)d_in[0];
    const float* W_ih  = (const float*)d_in[1];
    const float* W_hh  = (const float*)d_in[2];
    const float* b_ih  = (const float*)d_in[3];
    const float* b_hh  = (const float*)d_in[4];
    const float* W_out = (const float*)d_in[5];
    const float* b_out = (const float*)d_in[6];
    const float* mask  = (const float*)d_in[7];
    float* out = (float*)d_out;

    dim3 block(256);
    dim3 grid(kB / kGB);                 // 1024 blocks
    dprnn_kernel<<<grid, block, 0, stream>>>(x, W_ih, W_hh, b_ih, b_hh,
                                             W_out, b_out, mask, out);
}

// Round 9
// 138.822 us; speedup vs baseline: 4.1200x; 4.1200x over previous
//
#include <hip/hip_runtime.h>

#ifndef __has_builtin
#define __has_builtin(x) 0
#endif

#if __has_builtin(__builtin_amdgcn_exp2f)
#define EXP2F(x) __builtin_amdgcn_exp2f(x)
#else
#define EXP2F(x) exp2f(x)
#endif

#if __has_builtin(__builtin_amdgcn_rcpf)
#define RCPF(x) __builtin_amdgcn_rcpf(x)
#else
#define RCPF(x) (1.0f / (x))
#endif

namespace {

constexpr int kB = 65536;
constexpr int kT = 50;
constexpr int kI = 2;
constexpr int kH = 20;
constexpr int kO = 2;
constexpr int kGB = 64;    // batch elements per block

__device__ __forceinline__ float fast_tanh(float v) {
    // tanh(v) = 1 - 2/(exp(2v)+1); v_exp_f32 saturates so no clamp needed
    const float p = EXP2F(v * 2.8853900817779268f);
    return fmaf(-2.0f, RCPF(p + 1.0f), 1.0f);
}

// Intra-quad lane exchange via DPP quad_perm (pure VALU, no DS latency).
// xor1: [1,0,3,2]=0xB1  xor2: [2,3,0,1]=0x4E  xor3: [3,2,1,0]=0x1B
#if __has_builtin(__builtin_amdgcn_mov_dpp)
template <int CTRL>
__device__ __forceinline__ float fqp(float v) {
    return __int_as_float(
        __builtin_amdgcn_mov_dpp(__float_as_int(v), CTRL, 0xF, 0xF, true));
}
#else
template <int CTRL>
__device__ __forceinline__ float fqp(float v) {
    constexpr int d = (CTRL == 0xB1) ? 1 : (CTRL == 0x4E) ? 2 : 3;
    return __shfl_xor(v, d);
}
#endif

// drop_mask is binary: keep/(1-0.2) is EXACTLY 0.0f or 1.25f in fp32.
// Phase 1: block reads its 64x50x20 fp32 mask region fully coalesced
// (sequential float4 stream -> ideal DRAM bursts) and compresses to
// 1 bit/element (8 KB LDS) via !=0 + 8-lane shuffle-OR.
// Phase 2: R2's proven quad-per-element recurrence; mask decoded from
// LDS bits (ds_read2 + alignbit + and/select), ZERO global mask traffic.
__global__ __launch_bounds__(256)
__attribute__((amdgpu_waves_per_eu(2, 3)))
void dprnn_kernel(
    const float* __restrict__ x, const float* __restrict__ W_ih,
    const float* __restrict__ W_hh, const float* __restrict__ b_ih,
    const float* __restrict__ b_hh, const float* __restrict__ W_out,
    const float* __restrict__ b_out, const float* __restrict__ mask,
    float* __restrict__ out)
{
    __shared__ uint32_t lds_bits[2048];                   //  8192 B (2000 used)
    __shared__ __align__(16) float lds_o[kGB * kT * kO];  // 25600 B

    const int tidx = threadIdx.x;
    const int gl   = tidx >> 2;          // quad index 0..63
    const int sub  = tidx & 3;           // quarter of H owned
    const size_t g = (size_t)blockIdx.x * kGB + gl;

    // ================= phase 1: mask -> bits =================
    {
        const float4* mb4 =
            (const float4*)(mask + (size_t)blockIdx.x * (kGB * kT * kH));
        const int shl = (tidx & 7) * 4;  // nibble position within dword
#pragma unroll 2
        for (int it = 0; it < 62; ++it) {
            const float4 v = mb4[it * 256 + tidx];
            uint32_t wd = ((__float_as_uint(v.x) ? 1u : 0u) |
                           (__float_as_uint(v.y) ? 2u : 0u) |
                           (__float_as_uint(v.z) ? 4u : 0u) |
                           (__float_as_uint(v.w) ? 8u : 0u)) << shl;
            wd |= (uint32_t)__shfl_xor((int)wd, 1);
            wd |= (uint32_t)__shfl_xor((int)wd, 2);
            wd |= (uint32_t)__shfl_xor((int)wd, 4);
            if ((tidx & 7) == 0) lds_bits[it * 32 + (tidx >> 3)] = wd;
        }
        // tail: float4s [15872, 16000) -> waves 0,1 fully active
        if (tidx < 128) {
            const float4 v = mb4[15872 + tidx];
            uint32_t wd = ((__float_as_uint(v.x) ? 1u : 0u) |
                           (__float_as_uint(v.y) ? 2u : 0u) |
                           (__float_as_uint(v.z) ? 4u : 0u) |
                           (__float_as_uint(v.w) ? 8u : 0u)) << shl;
            wd |= (uint32_t)__shfl_xor((int)wd, 1);
            wd |= (uint32_t)__shfl_xor((int)wd, 2);
            wd |= (uint32_t)__shfl_xor((int)wd, 4);
            if ((tidx & 7) == 0) lds_bits[1984 + (tidx >> 3)] = wd;
        }
    }
    __syncthreads();

    // ================= weights into registers =================
    float w[5][5][4];
    float wi0[5], wi1[5], bia[5], wo0[5], wo1[5];
#pragma unroll
    for (int i = 0; i < 5; ++i) {
        const int row = 4 * i + sub;
#pragma unroll
        for (int r = 0; r < 5; ++r)
#pragma unroll
            for (int d = 0; d < 4; ++d)
                w[i][r][d] = W_hh[row * kH + 4 * r + (sub ^ d)];
        wi0[i] = W_ih[row * kI + 0];
        wi1[i] = W_ih[row * kI + 1];
        bia[i] = b_ih[row] + b_hh[row];
        wo0[i] = W_out[row];
        wo1[i] = W_out[kH + row];
    }
    const float bo0 = b_out[0];
    const float bo1 = b_out[1];

    float h[5] = {0.f, 0.f, 0.f, 0.f, 0.f};
    const float* xp = x + g * (kT * kI);

    // one RNN step; wm bit 4i = this thread's dropout bit for row 4i+sub
    auto step = [&](uint32_t wm, float x0, float x1, int t) {
        float acc[5];
#pragma unroll
        for (int i = 0; i < 5; ++i)
            acc[i] = fmaf(wi0[i], x0, fmaf(wi1[i], x1, bia[i]));
#pragma unroll
        for (int r = 0; r < 5; ++r) {
            const float v0 = h[r];
            const float v1 = fqp<0xB1>(h[r]);
            const float v2 = fqp<0x4E>(h[r]);
            const float v3 = fqp<0x1B>(h[r]);
#pragma unroll
            for (int i = 0; i < 5; ++i) {
                acc[i] = fmaf(w[i][r][0], v0, acc[i]);
                acc[i] = fmaf(w[i][r][1], v1, acc[i]);
                acc[i] = fmaf(w[i][r][2], v2, acc[i]);
                acc[i] = fmaf(w[i][r][3], v3, acc[i]);
            }
        }
        float p0 = 0.f, p1 = 0.f;
#pragma unroll
        for (int i = 0; i < 5; ++i) {
            const float hn = fast_tanh(acc[i]);
            h[i] = hn;
            const float mi = (wm & (1u << (4 * i))) ? 1.25f : 0.0f;
            const float dm = hn * mi;
            p0 = fmaf(dm, wo0[i], p0);
            p1 = fmaf(dm, wo1[i], p1);
        }
        p0 += fqp<0xB1>(p0);
        p0 += fqp<0x4E>(p0);
        p1 += fqp<0xB1>(p1);
        p1 += fqp<0x4E>(p1);
        if (sub == 0)
            *(float2*)&lds_o[gl * (kT * kO) + t * kO] =
                make_float2(p0 + bo0, p1 + bo1);
    };

    // bit window for (gl, t): bits [gl*1000 + 20t, +20)
    auto getwin = [&](int p) -> uint32_t {
        const int d = p >> 5, sh = p & 31;
        const uint32_t lo = lds_bits[d];
        const uint32_t hi = lds_bits[d + 1];   // padded; garbage bits unused
        return (uint32_t)(((((uint64_t)hi) << 32) | lo) >> sh) >> sub;
    };

    // ================= phase 2: recurrence =================
    float4 xq = *(const float4*)xp;          // x for t=0,1
    int p = gl * 1000;
    for (int tb = 0; tb < kT - 2; tb += 2) {
        const float4 xn = *(const float4*)(xp + (tb + 2) * kI);
        step(getwin(p),      xq.x, xq.y, tb);
        step(getwin(p + 20), xq.z, xq.w, tb + 1);
        p += 40;
        xq = xn;
    }
    step(getwin(p),      xq.x, xq.y, kT - 2);
    step(getwin(p + 20), xq.z, xq.w, kT - 1);

    // ---- coalesced writeback of this block's 64*100 floats ----
    __syncthreads();
    float* ob = out + (size_t)blockIdx.x * (kGB * kT * kO);
#pragma unroll
    for (int it = 0; it < 6; ++it) {
        const int idx = it * 1024 + tidx * 4;
        const float4 v = *(const float4*)&lds_o[idx];
        *(float4*)(ob + idx) = v;
    }
    {
        const int idx = 6144 + tidx;
        ob[idx] = lds_o[idx];
    }
}

}  // namespace

extern "C" void kernel_launch(void* const* d_in, const int* in_sizes, int n_in,
                              void* d_out, int out_size, void* d_ws, size_t ws_size,
                              hipStream_t stream) {
    const float* x     = (const float*)d_in[0];
    const float* W_ih  = (const float*)d_in[1];
    const float* W_hh  = (const float*)d_in[2];
    const float* b_ih  = (const float*)d_in[3];
    const float* b_hh  = (const float*)d_in[4];
    const float* W_out = (const float*)d_in[5];
    const float* b_out = (const float*)d_in[6];
    const float* mask  = (const float*)d_in[7];
    float* out = (float*)d_out;

    dim3 block(256);
    dim3 grid(kB / kGB);                 // 1024 blocks
    dprnn_kernel<<<grid, block, 0, stream>>>(x, W_ih, W_hh, b_ih, b_hh,
                                             W_out, b_out, mask, out);
}